// Round 9
// baseline (223.751 us; speedup 1.0000x reference)
//
#include <hip/hip_runtime.h>

// ---------------- types ----------------
typedef __bf16 bf16x8 __attribute__((ext_vector_type(8)));
typedef __bf16 bf16x4 __attribute__((ext_vector_type(4)));
typedef float  f32x4  __attribute__((ext_vector_type(4)));
typedef short  s16x4  __attribute__((ext_vector_type(4)));

#define AS1 __attribute__((address_space(1)))
#define AS3 __attribute__((address_space(3)))

__device__ inline void gload_lds16(const void* g, void* l) {
  __builtin_amdgcn_global_load_lds((AS1 void*)(g), (AS3 void*)(l), 16, 0, 0);
}

#if __has_builtin(__builtin_amdgcn_exp2f)
#define EXP2(x) __builtin_amdgcn_exp2f(x)
#else
#define EXP2(x) exp2f(x)
#endif

#if __has_builtin(__builtin_amdgcn_mfma_f32_16x16x16bf16_1k)
#define PV_K16 1
#define MFMA16(a, b, c) __builtin_amdgcn_mfma_f32_16x16x16bf16_1k(a, b, c, 0, 0, 0)
#else
#define PV_K16 0
#endif

__device__ inline short bf2s(__bf16 x) {
  union { __bf16 b; short s; } u; u.b = x; return u.s;
}

// ---------------- constants ----------------
#define CB 2
#define CS 2048
#define CE 1024
#define CH 16
#define CD 64
#define GM 4096
#define GN 1024
#define GK 1024

// Q pre-scale: (1/sqrt(H)) * log2(e) so attn uses exp2 directly.
#define QSCALE 0.36067376022224087f

// workspace element offsets (__bf16 units)
#define WS_WQ  0
#define WS_WK  1048576
#define WS_WV  2097152
#define WS_WO  3145728
#define WS_XQ  4194304
#define WS_XK  8388608
#define WS_XV  12582912
#define WS_QH  16777216
#define WS_KH  20971520
#define WS_VT  25165824
#define WS_AO  WS_XQ   // Xq dead when attention writes AO

// ---------------- fp32 -> bf16 conversion (8 elems/thread, 16B stores) ----
__global__ __launch_bounds__(256) void convert_all(
    const float* __restrict__ q, const float* __restrict__ k, const float* __restrict__ v,
    const float* __restrict__ wq, const float* __restrict__ wk,
    const float* __restrict__ wv, const float* __restrict__ wo,
    __bf16* __restrict__ ws) {
  long idx = ((long)blockIdx.x * 256 + threadIdx.x) * 8;
  const float* src;
  __bf16* dst;
  if (idx < 12582912) {
    int a = (int)(idx >> 22);
    long within = idx & 4194303;
    src = (a == 0 ? q : (a == 1 ? k : v)) + within;
    dst = ws + WS_XQ + (long)a * 4194304 + within;
  } else {
    long widx = idx - 12582912;
    int a = (int)(widx >> 20);
    long within = widx & 1048575;
    src = (a == 0 ? wq : (a == 1 ? wk : (a == 2 ? wv : wo))) + within;
    dst = ws + widx;
  }
  float4 f0 = *(const float4*)src;
  float4 f1 = *(const float4*)(src + 4);
  bf16x8 o;
  o[0] = (__bf16)f0.x; o[1] = (__bf16)f0.y; o[2] = (__bf16)f0.z; o[3] = (__bf16)f0.w;
  o[4] = (__bf16)f1.x; o[5] = (__bf16)f1.y; o[6] = (__bf16)f1.z; o[7] = (__bf16)f1.w;
  *(bf16x8*)dst = o;
}

// ======== BK=64 GEMM core with XOR-swizzled LDS (R4, conflict-free) ========
// Bijective XCD-aware blockIdx swizzle (T1): each XCD owns a contiguous chunk
// of tile-space. Verified R0->R6: non-attn 170.2 -> ~164 with this.
// R8's mode-loop variant (512 blocks, modes serialized in-block) was +2us:
// reverted — mode-level parallelism (768 blocks, 3/CU) beats L2 set-shrink.
#define GEMM_BK64_BODY(A_PTR, B_PTR, KLEN)                                          \
  __shared__ __bf16 As[8192];                                                       \
  __shared__ __bf16 Bs[8192];                                                       \
  const int tid = threadIdx.x;                                                      \
  const int w = tid >> 6, l = tid & 63;                                             \
  const int wm = w >> 1, wn = w & 1;                                                \
  const int orig = blockIdx.y * gridDim.x + blockIdx.x;                             \
  const int cpx = (gridDim.x * gridDim.y) >> 3;                                     \
  const int wgid = (orig & 7) * cpx + (orig >> 3);                                  \
  const int bm = (wgid / gridDim.x) * 128, bn = (wgid % gridDim.x) * 128;           \
  const int lr = l & 15, lq = l >> 4;                                               \
  f32x4 acc[4][4] = {};                                                             \
  const int srow = w * 8 + (l >> 3);                                                \
  const int scol = ((l & 7) ^ ((l >> 3) & 7)) * 8;                                  \
  const __bf16* ga0 = (A_PTR) + (size_t)(bm + srow) * GK + scol;                    \
  const __bf16* gb0 = (B_PTR) + (size_t)(bn + srow) * GK + scol;                    \
  const int dstg = w * 64 + l;                                                      \
  for (int k0 = 0; k0 < (KLEN); k0 += 64) {                                         \
    __syncthreads();                                                                \
    for (int i = 0; i < 4; i++) {                                                   \
      gload_lds16(ga0 + (size_t)(i * 32) * GK + k0, &As[(i * 256 + dstg) * 8]);     \
      gload_lds16(gb0 + (size_t)(i * 32) * GK + k0, &Bs[(i * 256 + dstg) * 8]);     \
    }                                                                               \
    __syncthreads();                                                                \
    for (int kk = 0; kk < 2; kk++) {                                                \
      bf16x8 af[4], bfr[4];                                                         \
      for (int mi = 0; mi < 4; mi++) {                                              \
        const int row = wm * 64 + mi * 16 + lr;                                     \
        af[mi] = *(const bf16x8*)&As[(row * 8 + ((kk * 4 + lq) ^ (row & 7))) * 8];  \
      }                                                                             \
      for (int ni = 0; ni < 4; ni++) {                                              \
        const int row = wn * 64 + ni * 16 + lr;                                     \
        bfr[ni] = *(const bf16x8*)&Bs[(row * 8 + ((kk * 4 + lq) ^ (row & 7))) * 8]; \
      }                                                                             \
      for (int mi = 0; mi < 4; mi++)                                                \
        for (int ni = 0; ni < 4; ni++)                                              \
          acc[mi][ni] = __builtin_amdgcn_mfma_f32_16x16x32_bf16(af[mi], bfr[ni],    \
                                                                acc[mi][ni], 0, 0, 0); \
    }                                                                               \
  }

// ---------------- fused QKV GEMM: grid (8, 32, 3) — R6-verified ----------
__global__ __launch_bounds__(256) void qkv_gemm(
    const __bf16* __restrict__ Xq, const __bf16* __restrict__ Xk, const __bf16* __restrict__ Xv,
    const __bf16* __restrict__ Wq, const __bf16* __restrict__ Wk, const __bf16* __restrict__ Wv,
    const float* __restrict__ bq, const float* __restrict__ bk, const float* __restrict__ bv,
    __bf16* __restrict__ Qh, __bf16* __restrict__ Kh, __bf16* __restrict__ Vt) {
  const int mode = blockIdx.z;
  const __bf16* A  = mode == 0 ? Xq : (mode == 1 ? Xk : Xv);
  const __bf16* Bw = mode == 0 ? Wq : (mode == 1 ? Wk : Wv);
  const float* bias = mode == 0 ? bq : (mode == 1 ? bk : bv);

  GEMM_BK64_BODY(A, Bw, GK)

  const int row0 = bm + wm * 64;
  const int col0 = bn + wn * 64;
  for (int ni = 0; ni < 4; ni++) {
    const int col = col0 + ni * 16 + lr;
    const float bb = bias[col];
    for (int mi = 0; mi < 4; mi++) {
      const int row = row0 + mi * 16 + lq * 4;
      if (mode == 0) {
        for (int r = 0; r < 4; r++)
          Qh[(size_t)(row + r) * GN + col] = (__bf16)((acc[mi][ni][r] + bb) * QSCALE);
      } else if (mode == 1) {
        for (int r = 0; r < 4; r++)
          Kh[(size_t)(row + r) * GN + col] = (__bf16)(acc[mi][ni][r] + bb);
      } else {
        const int b = row >> 11, s = row & 2047;
        const int h = col >> 6, d = col & 63;
        bf16x4 pk;
        for (int r = 0; r < 4; r++) pk[r] = (__bf16)(acc[mi][ni][r] + bb);
        *(bf16x4*)&Vt[(size_t)((b * CH + h) * CD + d) * CS + s] = pk;
      }
    }
  }
}

// ---------------- Wo GEMM: 64x128 tile, grid (8, 64) = 2 blocks/CU --------
// R6-verified: 2 blocks/CU overlap the per-K-step drains (total -3.7us).
__global__ __launch_bounds__(256) void gemm_wo(const __bf16* __restrict__ Ain,
                                               const __bf16* __restrict__ Bw,
                                               const float* __restrict__ bias,
                                               float* __restrict__ O) {
  __shared__ __bf16 As[4096];
  __shared__ __bf16 Bs[8192];
  const int tid = threadIdx.x;
  const int w = tid >> 6, l = tid & 63;
  const int orig = blockIdx.y * gridDim.x + blockIdx.x;
  const int cpx = (gridDim.x * gridDim.y) >> 3;
  const int wgid = (orig & 7) * cpx + (orig >> 3);
  const int bm = (wgid / gridDim.x) * 64, bn = (wgid % gridDim.x) * 128;
  const int lr = l & 15, lq = l >> 4;
  f32x4 acc[4][2] = {};
  const int srow = w * 8 + (l >> 3);
  const int scol = ((l & 7) ^ ((l >> 3) & 7)) * 8;
  const __bf16* ga0 = Ain + (size_t)(bm + srow) * GK + scol;
  const __bf16* gb0 = Bw + (size_t)(bn + srow) * GK + scol;
  const int dstg = w * 64 + l;
  for (int k0 = 0; k0 < GK; k0 += 64) {
    __syncthreads();
    for (int i = 0; i < 2; i++)
      gload_lds16(ga0 + (size_t)(i * 32) * GK + k0, &As[(i * 256 + dstg) * 8]);
    for (int i = 0; i < 4; i++)
      gload_lds16(gb0 + (size_t)(i * 32) * GK + k0, &Bs[(i * 256 + dstg) * 8]);
    __syncthreads();
    for (int kk = 0; kk < 2; kk++) {
      bf16x8 af[4], bfr[2];
      for (int mi = 0; mi < 4; mi++) {
        const int row = mi * 16 + lr;
        af[mi] = *(const bf16x8*)&As[(row * 8 + ((kk * 4 + lq) ^ (row & 7))) * 8];
      }
      for (int ni = 0; ni < 2; ni++) {
        const int row = w * 32 + ni * 16 + lr;
        bfr[ni] = *(const bf16x8*)&Bs[(row * 8 + ((kk * 4 + lq) ^ (row & 7))) * 8];
      }
      for (int mi = 0; mi < 4; mi++)
        for (int ni = 0; ni < 2; ni++)
          acc[mi][ni] = __builtin_amdgcn_mfma_f32_16x16x32_bf16(af[mi], bfr[ni],
                                                                acc[mi][ni], 0, 0, 0);
    }
  }

  for (int ni = 0; ni < 2; ni++) {
    const int col = bn + w * 32 + ni * 16 + lr;
    const float bb = bias[col];
    for (int mi = 0; mi < 4; mi++) {
      const int row = bm + mi * 16 + lq * 4;
      for (int r = 0; r < 4; r++)
        O[(size_t)(row + r) * GN + col] = acc[mi][ni][r] + bb;
    }
  }
}

// ---------------- fused flash attention v6 + head-per-XCD clustering -----
// Compute body FROZEN (R0/R5/R6/R8-verified 57.4us; falsified axes: R1
// dbuf/vmcnt 70.7, R2 more-blocks 90.9, R3 bigger-stage 153.5, R7 8-wave
// 1-block/CU 69.5 — see session journal).
// R9 change is INDEX-ONLY (T1 mechanism, 3rd application): hardware assigns
// XCD ~ dispatch_index%8 and index%8 == blockIdx.x%8 (gridDim.x=32). Old
// bh=blockIdx.x made every XCD touch all 32 heads' K/V (~8MB >> 4MB L2).
// New bh=(bx&7)*4+(bx>>3): XCD bx%8 serves exactly 4 heads (1MB K/V,
// L2-resident) and ALL 16 q-blocks of a head stay on one XCD (32%8==0 so
// XCD is by-invariant). Bijective over bx in [0,32). Staging loads turn
// L3-latency (~400-600cy) into L2-latency (~200cy), shrinking the exposed
// per-tile drain.
__global__ __launch_bounds__(256, 2) void attn(const __bf16* __restrict__ Qh,
                                               const __bf16* __restrict__ Kh,
                                               const __bf16* __restrict__ Vt,
                                               __bf16* __restrict__ AO) {
  // Ks: [dchunk j 0..7][keyslot 0..127][8], keyslot = key ^ (2*(j&3))
  // Vs: [keychunk j2 0..15][dslot 0..63][8], dslot = d ^ (4*(j2&1))
  __shared__ __bf16 Ks[8192];
  __shared__ __bf16 Vs[8192];

  const int tid = threadIdx.x, w = tid >> 6, l = tid & 63;
  const int lr = l & 15, lq = l >> 4;
  const int bx = blockIdx.x;
  const int bh = (bx & 7) * 4 + (bx >> 3);   // head-per-XCD clustering (R9)
  const int b = bh >> 4, h = bh & 15;
  const int q0 = blockIdx.y * 128 + w * 32;

  // Q as B-operand: B[n=q][k=d=kk*32+lq*8+j]  (Qh pre-scaled by QSCALE)
  bf16x8 qf[2][2];
  for (int mi = 0; mi < 2; mi++)
    for (int kk = 0; kk < 2; kk++)
      qf[mi][kk] = *(const bf16x8*)&Qh[((size_t)b * CS + q0 + mi * 16 + lr) * CE + h * CD + kk * 32 + lq * 8];

  f32x4 o[2][4] = {};
  float lsum[2] = {0.f, 0.f};
#if !PV_K16
  const bool hi_half = (lq & 1);
#endif

  for (int kt = 0; kt < CS / 128; kt++) {
    __syncthreads();
    // staging (R3-verified): K chunk j = w*2+(i>>1), half = i&1; V keychunk j2
    for (int i = 0; i < 4; i++) {
      const int j = w * 2 + (i >> 1), hf = i & 1;
      const int key = (hf * 64 + l) ^ ((j & 3) * 2);
      gload_lds16(&Kh[((size_t)b * CS + kt * 128 + key) * CE + h * CD + j * 8],
                  &Ks[(j * 128 + hf * 64) * 8]);
    }
    for (int i = 0; i < 4; i++) {
      const int j2 = w * 4 + i;
      const int d = l ^ ((j2 & 1) * 4);
      gload_lds16(&Vt[((size_t)bh * CD + d) * CS + kt * 128 + j2 * 8],
                  &Vs[(j2 * 64) * 8]);
    }
    __syncthreads();

    // S^T = K.Q^T : sa[mi][ni][r] <-> key = ni*16+lq*4+r, q = q0+mi*16+lr
    f32x4 sa[2][8] = {};
    for (int kk = 0; kk < 2; kk++) {
      bf16x8 kf[8];
      for (int ni = 0; ni < 8; ni++)
        kf[ni] = *(const bf16x8*)&Ks[((kk * 4 + lq) * 128 + ((ni * 16 + lr) ^ (lq * 2))) * 8];
      for (int mi = 0; mi < 2; mi++)
        for (int ni = 0; ni < 8; ni++)
          sa[mi][ni] = __builtin_amdgcn_mfma_f32_16x16x32_bf16(kf[ni], qf[mi][kk], sa[mi][ni], 0, 0, 0);
    }

#if PV_K16
    // exp2 + direct K=16 A-frag; V b64 frags shared across both q-halves
    for (int ni = 0; ni < 8; ni++) {
      s16x4 pa4[2];
      for (int mi = 0; mi < 2; mi++)
        for (int r = 0; r < 4; r++) {
          const float p = EXP2(sa[mi][ni][r]);
          lsum[mi] += p;
          pa4[mi][r] = bf2s((__bf16)p);
        }
      const int j2 = ni * 2 + (lq >> 1);
      const int base = j2 * 64;
      const int sw = (j2 & 1) * 4;
      for (int di = 0; di < 4; di++) {
        const int dslot = (di * 16 + lr) ^ sw;
        const s16x4 vb4 = *(const s16x4*)&Vs[(base + dslot) * 8 + (lq & 1) * 4];
        for (int mi = 0; mi < 2; mi++)
          o[mi][di] = MFMA16(pa4[mi], vb4, o[mi][di]);
      }
    }
#else
    // fallback: zero-padded K=32 PV
    for (int ni = 0; ni < 8; ni++) {
      bf16x8 pa[2];
      for (int mi = 0; mi < 2; mi++) {
        bf16x8 f;
        for (int r = 0; r < 4; r++) {
          const float p = EXP2(sa[mi][ni][r]);
          lsum[mi] += p;
          const __bf16 bv2 = (__bf16)p;
          f[r]     = hi_half ? (__bf16)0.f : bv2;
          f[4 + r] = hi_half ? bv2 : (__bf16)0.f;
        }
        pa[mi] = f;
      }
      for (int di = 0; di < 4; di++) {
        const bf16x8 vbf = *(const bf16x8*)&Vs[((ni * 2 + (lq >> 1)) * 64 + ((di * 16 + lr) ^ ((lq >> 1) * 4))) * 8];
        for (int mi = 0; mi < 2; mi++)
          o[mi][di] = __builtin_amdgcn_mfma_f32_16x16x32_bf16(pa[mi], vbf, o[mi][di], 0, 0, 0);
      }
    }
#endif
  }

  // deferred row-sum: lane partial for q = q0+mi*16+lr over keys {16ni+lq*4+r}
  for (int mi = 0; mi < 2; mi++) {
    lsum[mi] += __shfl_xor(lsum[mi], 16, 64);
    lsum[mi] += __shfl_xor(lsum[mi], 32, 64);
  }

  // o C-layout: row q_local = lq*4+r, col d = di*16+lr
  for (int mi = 0; mi < 2; mi++) {
    f32x4 rv;
    for (int r = 0; r < 4; r++) rv[r] = 1.0f / __shfl(lsum[mi], lq * 4 + r, 64);
    for (int di = 0; di < 4; di++)
      for (int r = 0; r < 4; r++) {
        const size_t s = q0 + mi * 16 + lq * 4 + r;
        AO[((size_t)b * CS + s) * CE + h * CD + di * 16 + lr] = (__bf16)(o[mi][di][r] * rv[r]);
      }
  }
}

// ---------------- launch ----------------
extern "C" void kernel_launch(void* const* d_in, const int* in_sizes, int n_in,
                              void* d_out, int out_size, void* d_ws, size_t ws_size,
                              hipStream_t stream) {
  (void)in_sizes; (void)n_in; (void)out_size; (void)ws_size;
  const float* q  = (const float*)d_in[0];
  const float* k  = (const float*)d_in[1];
  const float* v  = (const float*)d_in[2];
  const float* Wq = (const float*)d_in[3];
  const float* bq = (const float*)d_in[4];
  const float* Wk = (const float*)d_in[5];
  const float* bk = (const float*)d_in[6];
  const float* Wv = (const float*)d_in[7];
  const float* bv = (const float*)d_in[8];
  const float* Wo = (const float*)d_in[9];
  const float* bo = (const float*)d_in[10];

  __bf16* ws = (__bf16*)d_ws;
  __bf16 *Wq_b = ws + WS_WQ, *Wk_b = ws + WS_WK, *Wv_b = ws + WS_WV, *Wo_b = ws + WS_WO;
  __bf16 *Xq = ws + WS_XQ, *Xk = ws + WS_XK, *Xv = ws + WS_XV;
  __bf16 *Qh = ws + WS_QH, *Kh = ws + WS_KH, *Vt = ws + WS_VT;
  __bf16 *AO = ws + WS_AO;

  convert_all<<<8192, 256, 0, stream>>>(q, k, v, Wq, Wk, Wv, Wo, ws);

  qkv_gemm<<<dim3(GN / 128, GM / 128, 3), 256, 0, stream>>>(
      Xq, Xk, Xv, Wq_b, Wk_b, Wv_b, bq, bk, bv, Qh, Kh, Vt);

  attn<<<dim3(CB * CH, CS / 128), 256, 0, stream>>>(Qh, Kh, Vt, AO);

  gemm_wo<<<dim3(GN / 128, GM / 64), 256, 0, stream>>>(AO, Wo_b, bo, (float*)d_out);
}

// Round 10
// 221.418 us; speedup vs baseline: 1.0105x; 1.0105x over previous
//
#include <hip/hip_runtime.h>

// ---------------- types ----------------
typedef __bf16 bf16x8 __attribute__((ext_vector_type(8)));
typedef __bf16 bf16x4 __attribute__((ext_vector_type(4)));
typedef float  f32x4  __attribute__((ext_vector_type(4)));
typedef short  s16x4  __attribute__((ext_vector_type(4)));

#define AS1 __attribute__((address_space(1)))
#define AS3 __attribute__((address_space(3)))

__device__ inline void gload_lds16(const void* g, void* l) {
  __builtin_amdgcn_global_load_lds((AS1 void*)(g), (AS3 void*)(l), 16, 0, 0);
}

#if __has_builtin(__builtin_amdgcn_exp2f)
#define EXP2(x) __builtin_amdgcn_exp2f(x)
#else
#define EXP2(x) exp2f(x)
#endif

#if __has_builtin(__builtin_amdgcn_mfma_f32_16x16x16bf16_1k)
#define PV_K16 1
#define MFMA16(a, b, c) __builtin_amdgcn_mfma_f32_16x16x16bf16_1k(a, b, c, 0, 0, 0)
#else
#define PV_K16 0
#endif

__device__ inline short bf2s(__bf16 x) {
  union { __bf16 b; short s; } u; u.b = x; return u.s;
}

// ---------------- constants ----------------
#define CB 2
#define CS 2048
#define CE 1024
#define CH 16
#define CD 64
#define GM 4096
#define GN 1024
#define GK 1024

// Q pre-scale: (1/sqrt(H)) * log2(e) so attn uses exp2 directly.
#define QSCALE 0.36067376022224087f

// workspace element offsets (__bf16 units)
#define WS_WQ  0
#define WS_WK  1048576
#define WS_WV  2097152
#define WS_WO  3145728
#define WS_QH  16777216
#define WS_KH  20971520
#define WS_VT  25165824
#define WS_AO  4194304   // (old Xq region — unused by R10 fused staging)

// ---------------- fp32 -> bf16 weight conversion only (R10) --------------
// Q/K/V conversion is now fused into qkv_gemm's A-staging (in-register cvt
// during reg-staging), deleting the ~100MB X round-trip. Weights stay
// pre-converted: each W panel is re-read by 32 blocks, so converting once
// here is cheaper than 32x in-flight cvt + fp32 re-reads.
__global__ __launch_bounds__(256) void convert_w(
    const float* __restrict__ wq, const float* __restrict__ wk,
    const float* __restrict__ wv, const float* __restrict__ wo,
    __bf16* __restrict__ ws) {
  long widx = ((long)blockIdx.x * 256 + threadIdx.x) * 8;
  int a = (int)(widx >> 20);
  long within = widx & 1048575;
  const float* src = (a == 0 ? wq : (a == 1 ? wk : (a == 2 ? wv : wo))) + within;
  __bf16* dst = ws + widx;
  float4 f0 = *(const float4*)src;
  float4 f1 = *(const float4*)(src + 4);
  bf16x8 o;
  o[0] = (__bf16)f0.x; o[1] = (__bf16)f0.y; o[2] = (__bf16)f0.z; o[3] = (__bf16)f0.w;
  o[4] = (__bf16)f1.x; o[5] = (__bf16)f1.y; o[6] = (__bf16)f1.z; o[7] = (__bf16)f1.w;
  *(bf16x8*)dst = o;
}

// ---------------- fused QKV GEMM v3: fp32-A reg-staged + cvt (R10) -------
// Structure = R6-verified 128x128 m97-style body + T1 swizzle. A-staging
// replaced: load fp32 source (2x float4/lane, issued BEFORE the staging
// barrier so latency sits where gload_lds latency used to), convert in
// register, ds_write_b128 to the BYTE-IDENTICAL swizzled LDS slot (same
// (i*256+dstg)*8 dest, same pre-XOR'd source col) — layout unchanged,
// transport only. B-staging keeps gload_lds from pre-converted weights.
__global__ __launch_bounds__(256, 3) void qkv_gemm(
    const float* __restrict__ Aq, const float* __restrict__ Ak, const float* __restrict__ Av,
    const __bf16* __restrict__ Wq, const __bf16* __restrict__ Wk, const __bf16* __restrict__ Wv,
    const float* __restrict__ bq, const float* __restrict__ bk, const float* __restrict__ bv,
    __bf16* __restrict__ Qh, __bf16* __restrict__ Kh, __bf16* __restrict__ Vt) {
  const int mode = blockIdx.z;
  const float* A   = mode == 0 ? Aq : (mode == 1 ? Ak : Av);
  const __bf16* Bw = mode == 0 ? Wq : (mode == 1 ? Wk : Wv);
  const float* bias = mode == 0 ? bq : (mode == 1 ? bk : bv);

  __shared__ __bf16 As[8192];
  __shared__ __bf16 Bs[8192];
  const int tid = threadIdx.x;
  const int w = tid >> 6, l = tid & 63;
  const int wm = w >> 1, wn = w & 1;
  const int orig = blockIdx.y * gridDim.x + blockIdx.x;
  const int cpx = (gridDim.x * gridDim.y) >> 3;
  const int wgid = (orig & 7) * cpx + (orig >> 3);
  const int bm = (wgid / gridDim.x) * 128, bn = (wgid % gridDim.x) * 128;
  const int lr = l & 15, lq = l >> 4;
  f32x4 acc[4][4] = {};
  const int srow = w * 8 + (l >> 3);
  const int scol = ((l & 7) ^ ((l >> 3) & 7)) * 8;
  const float*  ga0 = A  + (size_t)(bm + srow) * GK + scol;
  const __bf16* gb0 = Bw + (size_t)(bn + srow) * GK + scol;
  const int dstg = w * 64 + l;

  for (int k0 = 0; k0 < GK; k0 += 64) {
    // A fp32 loads issued before the barrier: latency overlaps prior
    // compute drain + barrier sync, same position the old gload_lds had.
    float4 a0[4], a1[4];
    for (int i = 0; i < 4; i++) {
      const float* src = ga0 + (size_t)(i * 32) * GK + k0;
      a0[i] = *(const float4*)src;
      a1[i] = *(const float4*)(src + 4);
    }
    __syncthreads();
    for (int i = 0; i < 4; i++) {
      bf16x8 o8;
      o8[0] = (__bf16)a0[i].x; o8[1] = (__bf16)a0[i].y;
      o8[2] = (__bf16)a0[i].z; o8[3] = (__bf16)a0[i].w;
      o8[4] = (__bf16)a1[i].x; o8[5] = (__bf16)a1[i].y;
      o8[6] = (__bf16)a1[i].z; o8[7] = (__bf16)a1[i].w;
      *(bf16x8*)&As[(i * 256 + dstg) * 8] = o8;
      gload_lds16(gb0 + (size_t)(i * 32) * GK + k0, &Bs[(i * 256 + dstg) * 8]);
    }
    __syncthreads();
    for (int kk = 0; kk < 2; kk++) {
      bf16x8 af[4], bfr[4];
      for (int mi = 0; mi < 4; mi++) {
        const int row = wm * 64 + mi * 16 + lr;
        af[mi] = *(const bf16x8*)&As[(row * 8 + ((kk * 4 + lq) ^ (row & 7))) * 8];
      }
      for (int ni = 0; ni < 4; ni++) {
        const int row = wn * 64 + ni * 16 + lr;
        bfr[ni] = *(const bf16x8*)&Bs[(row * 8 + ((kk * 4 + lq) ^ (row & 7))) * 8];
      }
      for (int mi = 0; mi < 4; mi++)
        for (int ni = 0; ni < 4; ni++)
          acc[mi][ni] = __builtin_amdgcn_mfma_f32_16x16x32_bf16(af[mi], bfr[ni],
                                                                acc[mi][ni], 0, 0, 0);
    }
  }

  const int row0 = bm + wm * 64;
  const int col0 = bn + wn * 64;
  for (int ni = 0; ni < 4; ni++) {
    const int col = col0 + ni * 16 + lr;
    const float bb = bias[col];
    for (int mi = 0; mi < 4; mi++) {
      const int row = row0 + mi * 16 + lq * 4;
      if (mode == 0) {
        for (int r = 0; r < 4; r++)
          Qh[(size_t)(row + r) * GN + col] = (__bf16)((acc[mi][ni][r] + bb) * QSCALE);
      } else if (mode == 1) {
        for (int r = 0; r < 4; r++)
          Kh[(size_t)(row + r) * GN + col] = (__bf16)(acc[mi][ni][r] + bb);
      } else {
        const int b = row >> 11, s = row & 2047;
        const int h = col >> 6, d = col & 63;
        bf16x4 pk;
        for (int r = 0; r < 4; r++) pk[r] = (__bf16)(acc[mi][ni][r] + bb);
        *(bf16x4*)&Vt[(size_t)((b * CH + h) * CD + d) * CS + s] = pk;
      }
    }
  }
}

// ---------------- Wo GEMM: 64x128 tile, grid (8, 64) = 2 blocks/CU --------
// R6-verified: 2 blocks/CU overlap the per-K-step drains (total -3.7us).
__global__ __launch_bounds__(256) void gemm_wo(const __bf16* __restrict__ Ain,
                                               const __bf16* __restrict__ Bw,
                                               const float* __restrict__ bias,
                                               float* __restrict__ O) {
  __shared__ __bf16 As[4096];
  __shared__ __bf16 Bs[8192];
  const int tid = threadIdx.x;
  const int w = tid >> 6, l = tid & 63;
  const int orig = blockIdx.y * gridDim.x + blockIdx.x;
  const int cpx = (gridDim.x * gridDim.y) >> 3;
  const int wgid = (orig & 7) * cpx + (orig >> 3);
  const int bm = (wgid / gridDim.x) * 64, bn = (wgid % gridDim.x) * 128;
  const int lr = l & 15, lq = l >> 4;
  f32x4 acc[4][2] = {};
  const int srow = w * 8 + (l >> 3);
  const int scol = ((l & 7) ^ ((l >> 3) & 7)) * 8;
  const __bf16* ga0 = Ain + (size_t)(bm + srow) * GK + scol;
  const __bf16* gb0 = Bw + (size_t)(bn + srow) * GK + scol;
  const int dstg = w * 64 + l;
  for (int k0 = 0; k0 < GK; k0 += 64) {
    __syncthreads();
    for (int i = 0; i < 2; i++)
      gload_lds16(ga0 + (size_t)(i * 32) * GK + k0, &As[(i * 256 + dstg) * 8]);
    for (int i = 0; i < 4; i++)
      gload_lds16(gb0 + (size_t)(i * 32) * GK + k0, &Bs[(i * 256 + dstg) * 8]);
    __syncthreads();
    for (int kk = 0; kk < 2; kk++) {
      bf16x8 af[4], bfr[2];
      for (int mi = 0; mi < 4; mi++) {
        const int row = mi * 16 + lr;
        af[mi] = *(const bf16x8*)&As[(row * 8 + ((kk * 4 + lq) ^ (row & 7))) * 8];
      }
      for (int ni = 0; ni < 2; ni++) {
        const int row = w * 32 + ni * 16 + lr;
        bfr[ni] = *(const bf16x8*)&Bs[(row * 8 + ((kk * 4 + lq) ^ (row & 7))) * 8];
      }
      for (int mi = 0; mi < 4; mi++)
        for (int ni = 0; ni < 2; ni++)
          acc[mi][ni] = __builtin_amdgcn_mfma_f32_16x16x32_bf16(af[mi], bfr[ni],
                                                                acc[mi][ni], 0, 0, 0);
    }
  }

  for (int ni = 0; ni < 2; ni++) {
    const int col = bn + w * 32 + ni * 16 + lr;
    const float bb = bias[col];
    for (int mi = 0; mi < 4; mi++) {
      const int row = bm + mi * 16 + lq * 4;
      for (int r = 0; r < 4; r++)
        O[(size_t)(row + r) * GN + col] = acc[mi][ni][r] + bb;
    }
  }
}

// ---------------- fused flash attention v6 + head-per-XCD clustering -----
// FROZEN at 57.0-57.6us (R0/R5/R6/R8/R9). Falsified axes: R1 dbuf/vmcnt
// 70.7; R2 more-blocks 90.9; R3 bigger-stage 153.5 (spill); R7 8-wave
// 1-block/CU 69.5 (FETCH unchanged — K/V already L2-absorbed). R9's
// head-per-XCD clustering kept (index-only, -0.35us, directionally right).
__global__ __launch_bounds__(256, 2) void attn(const __bf16* __restrict__ Qh,
                                               const __bf16* __restrict__ Kh,
                                               const __bf16* __restrict__ Vt,
                                               __bf16* __restrict__ AO) {
  // Ks: [dchunk j 0..7][keyslot 0..127][8], keyslot = key ^ (2*(j&3))
  // Vs: [keychunk j2 0..15][dslot 0..63][8], dslot = d ^ (4*(j2&1))
  __shared__ __bf16 Ks[8192];
  __shared__ __bf16 Vs[8192];

  const int tid = threadIdx.x, w = tid >> 6, l = tid & 63;
  const int lr = l & 15, lq = l >> 4;
  const int bx = blockIdx.x;
  const int bh = (bx & 7) * 4 + (bx >> 3);   // head-per-XCD clustering (R9)
  const int b = bh >> 4, h = bh & 15;
  const int q0 = blockIdx.y * 128 + w * 32;

  // Q as B-operand: B[n=q][k=d=kk*32+lq*8+j]  (Qh pre-scaled by QSCALE)
  bf16x8 qf[2][2];
  for (int mi = 0; mi < 2; mi++)
    for (int kk = 0; kk < 2; kk++)
      qf[mi][kk] = *(const bf16x8*)&Qh[((size_t)b * CS + q0 + mi * 16 + lr) * CE + h * CD + kk * 32 + lq * 8];

  f32x4 o[2][4] = {};
  float lsum[2] = {0.f, 0.f};
#if !PV_K16
  const bool hi_half = (lq & 1);
#endif

  for (int kt = 0; kt < CS / 128; kt++) {
    __syncthreads();
    // staging (R3-verified): K chunk j = w*2+(i>>1), half = i&1; V keychunk j2
    for (int i = 0; i < 4; i++) {
      const int j = w * 2 + (i >> 1), hf = i & 1;
      const int key = (hf * 64 + l) ^ ((j & 3) * 2);
      gload_lds16(&Kh[((size_t)b * CS + kt * 128 + key) * CE + h * CD + j * 8],
                  &Ks[(j * 128 + hf * 64) * 8]);
    }
    for (int i = 0; i < 4; i++) {
      const int j2 = w * 4 + i;
      const int d = l ^ ((j2 & 1) * 4);
      gload_lds16(&Vt[((size_t)bh * CD + d) * CS + kt * 128 + j2 * 8],
                  &Vs[(j2 * 64) * 8]);
    }
    __syncthreads();

    // S^T = K.Q^T : sa[mi][ni][r] <-> key = ni*16+lq*4+r, q = q0+mi*16+lr
    f32x4 sa[2][8] = {};
    for (int kk = 0; kk < 2; kk++) {
      bf16x8 kf[8];
      for (int ni = 0; ni < 8; ni++)
        kf[ni] = *(const bf16x8*)&Ks[((kk * 4 + lq) * 128 + ((ni * 16 + lr) ^ (lq * 2))) * 8];
      for (int mi = 0; mi < 2; mi++)
        for (int ni = 0; ni < 8; ni++)
          sa[mi][ni] = __builtin_amdgcn_mfma_f32_16x16x32_bf16(kf[ni], qf[mi][kk], sa[mi][ni], 0, 0, 0);
    }

#if PV_K16
    // exp2 + direct K=16 A-frag; V b64 frags shared across both q-halves
    for (int ni = 0; ni < 8; ni++) {
      s16x4 pa4[2];
      for (int mi = 0; mi < 2; mi++)
        for (int r = 0; r < 4; r++) {
          const float p = EXP2(sa[mi][ni][r]);
          lsum[mi] += p;
          pa4[mi][r] = bf2s((__bf16)p);
        }
      const int j2 = ni * 2 + (lq >> 1);
      const int base = j2 * 64;
      const int sw = (j2 & 1) * 4;
      for (int di = 0; di < 4; di++) {
        const int dslot = (di * 16 + lr) ^ sw;
        const s16x4 vb4 = *(const s16x4*)&Vs[(base + dslot) * 8 + (lq & 1) * 4];
        for (int mi = 0; mi < 2; mi++)
          o[mi][di] = MFMA16(pa4[mi], vb4, o[mi][di]);
      }
    }
#else
    // fallback: zero-padded K=32 PV
    for (int ni = 0; ni < 8; ni++) {
      bf16x8 pa[2];
      for (int mi = 0; mi < 2; mi++) {
        bf16x8 f;
        for (int r = 0; r < 4; r++) {
          const float p = EXP2(sa[mi][ni][r]);
          lsum[mi] += p;
          const __bf16 bv2 = (__bf16)p;
          f[r]     = hi_half ? (__bf16)0.f : bv2;
          f[4 + r] = hi_half ? bv2 : (__bf16)0.f;
        }
        pa[mi] = f;
      }
      for (int di = 0; di < 4; di++) {
        const bf16x8 vbf = *(const bf16x8*)&Vs[((ni * 2 + (lq >> 1)) * 64 + ((di * 16 + lr) ^ ((lq >> 1) * 4))) * 8];
        for (int mi = 0; mi < 2; mi++)
          o[mi][di] = __builtin_amdgcn_mfma_f32_16x16x32_bf16(pa[mi], vbf, o[mi][di], 0, 0, 0);
      }
    }
#endif
  }

  // deferred row-sum: lane partial for q = q0+mi*16+lr over keys {16ni+lq*4+r}
  for (int mi = 0; mi < 2; mi++) {
    lsum[mi] += __shfl_xor(lsum[mi], 16, 64);
    lsum[mi] += __shfl_xor(lsum[mi], 32, 64);
  }

  // o C-layout: row q_local = lq*4+r, col d = di*16+lr
  for (int mi = 0; mi < 2; mi++) {
    f32x4 rv;
    for (int r = 0; r < 4; r++) rv[r] = 1.0f / __shfl(lsum[mi], lq * 4 + r, 64);
    for (int di = 0; di < 4; di++)
      for (int r = 0; r < 4; r++) {
        const size_t s = q0 + mi * 16 + lq * 4 + r;
        AO[((size_t)b * CS + s) * CE + h * CD + di * 16 + lr] = (__bf16)(o[mi][di][r] * rv[r]);
      }
  }
}

// ---------------- launch ----------------
extern "C" void kernel_launch(void* const* d_in, const int* in_sizes, int n_in,
                              void* d_out, int out_size, void* d_ws, size_t ws_size,
                              hipStream_t stream) {
  (void)in_sizes; (void)n_in; (void)out_size; (void)ws_size;
  const float* q  = (const float*)d_in[0];
  const float* k  = (const float*)d_in[1];
  const float* v  = (const float*)d_in[2];
  const float* Wq = (const float*)d_in[3];
  const float* bq = (const float*)d_in[4];
  const float* Wk = (const float*)d_in[5];
  const float* bk = (const float*)d_in[6];
  const float* Wv = (const float*)d_in[7];
  const float* bv = (const float*)d_in[8];
  const float* Wo = (const float*)d_in[9];
  const float* bo = (const float*)d_in[10];

  __bf16* ws = (__bf16*)d_ws;
  __bf16 *Wq_b = ws + WS_WQ, *Wk_b = ws + WS_WK, *Wv_b = ws + WS_WV, *Wo_b = ws + WS_WO;
  __bf16 *Qh = ws + WS_QH, *Kh = ws + WS_KH, *Vt = ws + WS_VT;
  __bf16 *AO = ws + WS_AO;

  convert_w<<<2048, 256, 0, stream>>>(Wq, Wk, Wv, Wo, ws);

  qkv_gemm<<<dim3(GN / 128, GM / 128, 3), 256, 0, stream>>>(
      q, k, v, Wq_b, Wk_b, Wv_b, bq, bk, bv, Qh, Kh, Vt);

  attn<<<dim3(CB * CH, CS / 128), 256, 0, stream>>>(Qh, Kh, Vt, AO);

  gemm_wo<<<dim3(GN / 128, GM / 64), 256, 0, stream>>>(AO, Wo_b, bo, (float*)d_out);
}

// Round 11
// 213.247 us; speedup vs baseline: 1.0493x; 1.0383x over previous
//
#include <hip/hip_runtime.h>

// ---------------- types ----------------
typedef __bf16 bf16x8 __attribute__((ext_vector_type(8)));
typedef __bf16 bf16x4 __attribute__((ext_vector_type(4)));
typedef float  f32x4  __attribute__((ext_vector_type(4)));
typedef short  s16x4  __attribute__((ext_vector_type(4)));

#define AS1 __attribute__((address_space(1)))
#define AS3 __attribute__((address_space(3)))

__device__ inline void gload_lds16(const void* g, void* l) {
  __builtin_amdgcn_global_load_lds((AS1 void*)(g), (AS3 void*)(l), 16, 0, 0);
}

#if __has_builtin(__builtin_amdgcn_exp2f)
#define EXP2(x) __builtin_amdgcn_exp2f(x)
#else
#define EXP2(x) exp2f(x)
#endif

#if __has_builtin(__builtin_amdgcn_mfma_f32_16x16x16bf16_1k)
#define PV_K16 1
#define MFMA16(a, b, c) __builtin_amdgcn_mfma_f32_16x16x16bf16_1k(a, b, c, 0, 0, 0)
#else
#define PV_K16 0
#endif

__device__ inline short bf2s(__bf16 x) {
  union { __bf16 b; short s; } u; u.b = x; return u.s;
}

// ---------------- constants ----------------
#define CB 2
#define CS 2048
#define CE 1024
#define CH 16
#define CD 64
#define GM 4096
#define GN 1024
#define GK 1024

// Q pre-scale: (1/sqrt(H)) * log2(e) so attn uses exp2 directly.
#define QSCALE 0.36067376022224087f

// workspace element offsets (__bf16 units)
#define WS_WQ  0
#define WS_WK  1048576
#define WS_WV  2097152
#define WS_WO  3145728
#define WS_QH  16777216
#define WS_KH  20971520
#define WS_VT  25165824
#define WS_AO  4194304

// ---------------- fp32 -> bf16 weight conversion only (R10) --------------
__global__ __launch_bounds__(256) void convert_w(
    const float* __restrict__ wq, const float* __restrict__ wk,
    const float* __restrict__ wv, const float* __restrict__ wo,
    __bf16* __restrict__ ws) {
  long widx = ((long)blockIdx.x * 256 + threadIdx.x) * 8;
  int a = (int)(widx >> 20);
  long within = widx & 1048575;
  const float* src = (a == 0 ? wq : (a == 1 ? wk : (a == 2 ? wv : wo))) + within;
  __bf16* dst = ws + widx;
  float4 f0 = *(const float4*)src;
  float4 f1 = *(const float4*)(src + 4);
  bf16x8 o;
  o[0] = (__bf16)f0.x; o[1] = (__bf16)f0.y; o[2] = (__bf16)f0.z; o[3] = (__bf16)f0.w;
  o[4] = (__bf16)f1.x; o[5] = (__bf16)f1.y; o[6] = (__bf16)f1.z; o[7] = (__bf16)f1.w;
  *(bf16x8*)dst = o;
}

// ---------------- fused QKV GEMM v4: fp32-A reg-staged, prefetched -------
// R10 counters: 57.2us, MfmaUtil 16.9, HBM 17.6%, all-low = latency-bound.
// Cause: A-loads issued right before barrier1, consumed right after ->
// full HBM latency (~900cy) exposed per k-step. R11: prefetch A(k0+64)
// AFTER barrier2, consume at NEXT iteration's cvt+ds_write — latency spans
// the 32-MFMA compute phase + barrier. Register loads carry no cross-wave
// hazard, so the compiler does not drain them at __syncthreads (unlike
// global_load_lds). B gloads issue before the cvt cluster (their latency
// hides under the cvt VALU work); B drain at barrier2 = verified R6 cost.
__global__ __launch_bounds__(256, 3) void qkv_gemm(
    const float* __restrict__ Aq, const float* __restrict__ Ak, const float* __restrict__ Av,
    const __bf16* __restrict__ Wq, const __bf16* __restrict__ Wk, const __bf16* __restrict__ Wv,
    const float* __restrict__ bq, const float* __restrict__ bk, const float* __restrict__ bv,
    __bf16* __restrict__ Qh, __bf16* __restrict__ Kh, __bf16* __restrict__ Vt) {
  const int mode = blockIdx.z;
  const float* A   = mode == 0 ? Aq : (mode == 1 ? Ak : Av);
  const __bf16* Bw = mode == 0 ? Wq : (mode == 1 ? Wk : Wv);
  const float* bias = mode == 0 ? bq : (mode == 1 ? bk : bv);

  __shared__ __bf16 As[8192];
  __shared__ __bf16 Bs[8192];
  const int tid = threadIdx.x;
  const int w = tid >> 6, l = tid & 63;
  const int wm = w >> 1, wn = w & 1;
  const int orig = blockIdx.y * gridDim.x + blockIdx.x;
  const int cpx = (gridDim.x * gridDim.y) >> 3;
  const int wgid = (orig & 7) * cpx + (orig >> 3);
  const int bm = (wgid / gridDim.x) * 128, bn = (wgid % gridDim.x) * 128;
  const int lr = l & 15, lq = l >> 4;
  f32x4 acc[4][4] = {};
  const int srow = w * 8 + (l >> 3);
  const int scol = ((l & 7) ^ ((l >> 3) & 7)) * 8;
  const float*  ga0 = A  + (size_t)(bm + srow) * GK + scol;
  const __bf16* gb0 = Bw + (size_t)(bn + srow) * GK + scol;
  const int dstg = w * 64 + l;

  // prologue: A regs for k0 = 0
  float4 a0[4], a1[4];
  for (int i = 0; i < 4; i++) {
    const float* src = ga0 + (size_t)(i * 32) * GK;
    a0[i] = *(const float4*)src;
    a1[i] = *(const float4*)(src + 4);
  }

  for (int k0 = 0; k0 < GK; k0 += 64) {
    __syncthreads();                       // prior compute done, LDS free
    // B staging first: HBM/L2 latency overlaps the cvt VALU work below
    for (int i = 0; i < 4; i++)
      gload_lds16(gb0 + (size_t)(i * 32) * GK + k0, &Bs[(i * 256 + dstg) * 8]);
    // consume prefetched A regs (wait lands here, already covered)
    for (int i = 0; i < 4; i++) {
      bf16x8 o8;
      o8[0] = (__bf16)a0[i].x; o8[1] = (__bf16)a0[i].y;
      o8[2] = (__bf16)a0[i].z; o8[3] = (__bf16)a0[i].w;
      o8[4] = (__bf16)a1[i].x; o8[5] = (__bf16)a1[i].y;
      o8[6] = (__bf16)a1[i].z; o8[7] = (__bf16)a1[i].w;
      *(bf16x8*)&As[(i * 256 + dstg) * 8] = o8;
    }
    __syncthreads();                       // drains B gloads + ds_writes
    // prefetch A for next k-step: in flight across the whole compute phase
    if (k0 + 64 < GK) {
      for (int i = 0; i < 4; i++) {
        const float* src = ga0 + (size_t)(i * 32) * GK + k0 + 64;
        a0[i] = *(const float4*)src;
        a1[i] = *(const float4*)(src + 4);
      }
    }
    for (int kk = 0; kk < 2; kk++) {
      bf16x8 af[4], bfr[4];
      for (int mi = 0; mi < 4; mi++) {
        const int row = wm * 64 + mi * 16 + lr;
        af[mi] = *(const bf16x8*)&As[(row * 8 + ((kk * 4 + lq) ^ (row & 7))) * 8];
      }
      for (int ni = 0; ni < 4; ni++) {
        const int row = wn * 64 + ni * 16 + lr;
        bfr[ni] = *(const bf16x8*)&Bs[(row * 8 + ((kk * 4 + lq) ^ (row & 7))) * 8];
      }
      for (int mi = 0; mi < 4; mi++)
        for (int ni = 0; ni < 4; ni++)
          acc[mi][ni] = __builtin_amdgcn_mfma_f32_16x16x32_bf16(af[mi], bfr[ni],
                                                                acc[mi][ni], 0, 0, 0);
    }
  }

  const int row0 = bm + wm * 64;
  const int col0 = bn + wn * 64;
  for (int ni = 0; ni < 4; ni++) {
    const int col = col0 + ni * 16 + lr;
    const float bb = bias[col];
    for (int mi = 0; mi < 4; mi++) {
      const int row = row0 + mi * 16 + lq * 4;
      if (mode == 0) {
        for (int r = 0; r < 4; r++)
          Qh[(size_t)(row + r) * GN + col] = (__bf16)((acc[mi][ni][r] + bb) * QSCALE);
      } else if (mode == 1) {
        for (int r = 0; r < 4; r++)
          Kh[(size_t)(row + r) * GN + col] = (__bf16)(acc[mi][ni][r] + bb);
      } else {
        const int b = row >> 11, s = row & 2047;
        const int h = col >> 6, d = col & 63;
        bf16x4 pk;
        for (int r = 0; r < 4; r++) pk[r] = (__bf16)(acc[mi][ni][r] + bb);
        *(bf16x4*)&Vt[(size_t)((b * CH + h) * CD + d) * CS + s] = pk;
      }
    }
  }
}

// ---------------- Wo GEMM: 64x128 tile, grid (8, 64) = 2 blocks/CU --------
// R6-verified: 2 blocks/CU overlap the per-K-step drains (total -3.7us).
__global__ __launch_bounds__(256) void gemm_wo(const __bf16* __restrict__ Ain,
                                               const __bf16* __restrict__ Bw,
                                               const float* __restrict__ bias,
                                               float* __restrict__ O) {
  __shared__ __bf16 As[4096];
  __shared__ __bf16 Bs[8192];
  const int tid = threadIdx.x;
  const int w = tid >> 6, l = tid & 63;
  const int orig = blockIdx.y * gridDim.x + blockIdx.x;
  const int cpx = (gridDim.x * gridDim.y) >> 3;
  const int wgid = (orig & 7) * cpx + (orig >> 3);
  const int bm = (wgid / gridDim.x) * 64, bn = (wgid % gridDim.x) * 128;
  const int lr = l & 15, lq = l >> 4;
  f32x4 acc[4][2] = {};
  const int srow = w * 8 + (l >> 3);
  const int scol = ((l & 7) ^ ((l >> 3) & 7)) * 8;
  const __bf16* ga0 = Ain + (size_t)(bm + srow) * GK + scol;
  const __bf16* gb0 = Bw + (size_t)(bn + srow) * GK + scol;
  const int dstg = w * 64 + l;
  for (int k0 = 0; k0 < GK; k0 += 64) {
    __syncthreads();
    for (int i = 0; i < 2; i++)
      gload_lds16(ga0 + (size_t)(i * 32) * GK + k0, &As[(i * 256 + dstg) * 8]);
    for (int i = 0; i < 4; i++)
      gload_lds16(gb0 + (size_t)(i * 32) * GK + k0, &Bs[(i * 256 + dstg) * 8]);
    __syncthreads();
    for (int kk = 0; kk < 2; kk++) {
      bf16x8 af[4], bfr[2];
      for (int mi = 0; mi < 4; mi++) {
        const int row = mi * 16 + lr;
        af[mi] = *(const bf16x8*)&As[(row * 8 + ((kk * 4 + lq) ^ (row & 7))) * 8];
      }
      for (int ni = 0; ni < 2; ni++) {
        const int row = w * 32 + ni * 16 + lr;
        bfr[ni] = *(const bf16x8*)&Bs[(row * 8 + ((kk * 4 + lq) ^ (row & 7))) * 8];
      }
      for (int mi = 0; mi < 4; mi++)
        for (int ni = 0; ni < 2; ni++)
          acc[mi][ni] = __builtin_amdgcn_mfma_f32_16x16x32_bf16(af[mi], bfr[ni],
                                                                acc[mi][ni], 0, 0, 0);
    }
  }

  for (int ni = 0; ni < 2; ni++) {
    const int col = bn + w * 32 + ni * 16 + lr;
    const float bb = bias[col];
    for (int mi = 0; mi < 4; mi++) {
      const int row = bm + mi * 16 + lq * 4;
      for (int r = 0; r < 4; r++)
        O[(size_t)(row + r) * GN + col] = acc[mi][ni][r] + bb;
    }
  }
}

// ---------------- fused flash attention v6 + head-per-XCD clustering -----
// FROZEN at 57.0-57.6us (R0/R5/R6/R8/R9/R10). Falsified axes: R1 dbuf/vmcnt
// 70.7; R2 more-blocks 90.9; R3 bigger-stage 153.5 (spill); R7 8-wave
// 1-block/CU 69.5 (FETCH unchanged — K/V already L2-absorbed). R9's
// head-per-XCD clustering kept (index-only, directionally right).
__global__ __launch_bounds__(256, 2) void attn(const __bf16* __restrict__ Qh,
                                               const __bf16* __restrict__ Kh,
                                               const __bf16* __restrict__ Vt,
                                               __bf16* __restrict__ AO) {
  // Ks: [dchunk j 0..7][keyslot 0..127][8], keyslot = key ^ (2*(j&3))
  // Vs: [keychunk j2 0..15][dslot 0..63][8], dslot = d ^ (4*(j2&1))
  __shared__ __bf16 Ks[8192];
  __shared__ __bf16 Vs[8192];

  const int tid = threadIdx.x, w = tid >> 6, l = tid & 63;
  const int lr = l & 15, lq = l >> 4;
  const int bx = blockIdx.x;
  const int bh = (bx & 7) * 4 + (bx >> 3);   // head-per-XCD clustering (R9)
  const int b = bh >> 4, h = bh & 15;
  const int q0 = blockIdx.y * 128 + w * 32;

  // Q as B-operand: B[n=q][k=d=kk*32+lq*8+j]  (Qh pre-scaled by QSCALE)
  bf16x8 qf[2][2];
  for (int mi = 0; mi < 2; mi++)
    for (int kk = 0; kk < 2; kk++)
      qf[mi][kk] = *(const bf16x8*)&Qh[((size_t)b * CS + q0 + mi * 16 + lr) * CE + h * CD + kk * 32 + lq * 8];

  f32x4 o[2][4] = {};
  float lsum[2] = {0.f, 0.f};
#if !PV_K16
  const bool hi_half = (lq & 1);
#endif

  for (int kt = 0; kt < CS / 128; kt++) {
    __syncthreads();
    // staging (R3-verified): K chunk j = w*2+(i>>1), half = i&1; V keychunk j2
    for (int i = 0; i < 4; i++) {
      const int j = w * 2 + (i >> 1), hf = i & 1;
      const int key = (hf * 64 + l) ^ ((j & 3) * 2);
      gload_lds16(&Kh[((size_t)b * CS + kt * 128 + key) * CE + h * CD + j * 8],
                  &Ks[(j * 128 + hf * 64) * 8]);
    }
    for (int i = 0; i < 4; i++) {
      const int j2 = w * 4 + i;
      const int d = l ^ ((j2 & 1) * 4);
      gload_lds16(&Vt[((size_t)bh * CD + d) * CS + kt * 128 + j2 * 8],
                  &Vs[(j2 * 64) * 8]);
    }
    __syncthreads();

    // S^T = K.Q^T : sa[mi][ni][r] <-> key = ni*16+lq*4+r, q = q0+mi*16+lr
    f32x4 sa[2][8] = {};
    for (int kk = 0; kk < 2; kk++) {
      bf16x8 kf[8];
      for (int ni = 0; ni < 8; ni++)
        kf[ni] = *(const bf16x8*)&Ks[((kk * 4 + lq) * 128 + ((ni * 16 + lr) ^ (lq * 2))) * 8];
      for (int mi = 0; mi < 2; mi++)
        for (int ni = 0; ni < 8; ni++)
          sa[mi][ni] = __builtin_amdgcn_mfma_f32_16x16x32_bf16(kf[ni], qf[mi][kk], sa[mi][ni], 0, 0, 0);
    }

#if PV_K16
    // exp2 + direct K=16 A-frag; V b64 frags shared across both q-halves
    for (int ni = 0; ni < 8; ni++) {
      s16x4 pa4[2];
      for (int mi = 0; mi < 2; mi++)
        for (int r = 0; r < 4; r++) {
          const float p = EXP2(sa[mi][ni][r]);
          lsum[mi] += p;
          pa4[mi][r] = bf2s((__bf16)p);
        }
      const int j2 = ni * 2 + (lq >> 1);
      const int base = j2 * 64;
      const int sw = (j2 & 1) * 4;
      for (int di = 0; di < 4; di++) {
        const int dslot = (di * 16 + lr) ^ sw;
        const s16x4 vb4 = *(const s16x4*)&Vs[(base + dslot) * 8 + (lq & 1) * 4];
        for (int mi = 0; mi < 2; mi++)
          o[mi][di] = MFMA16(pa4[mi], vb4, o[mi][di]);
      }
    }
#else
    // fallback: zero-padded K=32 PV
    for (int ni = 0; ni < 8; ni++) {
      bf16x8 pa[2];
      for (int mi = 0; mi < 2; mi++) {
        bf16x8 f;
        for (int r = 0; r < 4; r++) {
          const float p = EXP2(sa[mi][ni][r]);
          lsum[mi] += p;
          const __bf16 bv2 = (__bf16)p;
          f[r]     = hi_half ? (__bf16)0.f : bv2;
          f[4 + r] = hi_half ? bv2 : (__bf16)0.f;
        }
        pa[mi] = f;
      }
      for (int di = 0; di < 4; di++) {
        const bf16x8 vbf = *(const bf16x8*)&Vs[((ni * 2 + (lq >> 1)) * 64 + ((di * 16 + lr) ^ ((lq >> 1) * 4))) * 8];
        for (int mi = 0; mi < 2; mi++)
          o[mi][di] = __builtin_amdgcn_mfma_f32_16x16x32_bf16(pa[mi], vbf, o[mi][di], 0, 0, 0);
      }
    }
#endif
  }

  // deferred row-sum: lane partial for q = q0+mi*16+lr over keys {16ni+lq*4+r}
  for (int mi = 0; mi < 2; mi++) {
    lsum[mi] += __shfl_xor(lsum[mi], 16, 64);
    lsum[mi] += __shfl_xor(lsum[mi], 32, 64);
  }

  // o C-layout: row q_local = lq*4+r, col d = di*16+lr
  for (int mi = 0; mi < 2; mi++) {
    f32x4 rv;
    for (int r = 0; r < 4; r++) rv[r] = 1.0f / __shfl(lsum[mi], lq * 4 + r, 64);
    for (int di = 0; di < 4; di++)
      for (int r = 0; r < 4; r++) {
        const size_t s = q0 + mi * 16 + lq * 4 + r;
        AO[((size_t)b * CS + s) * CE + h * CD + di * 16 + lr] = (__bf16)(o[mi][di][r] * rv[r]);
      }
  }
}

// ---------------- launch ----------------
extern "C" void kernel_launch(void* const* d_in, const int* in_sizes, int n_in,
                              void* d_out, int out_size, void* d_ws, size_t ws_size,
                              hipStream_t stream) {
  (void)in_sizes; (void)n_in; (void)out_size; (void)ws_size;
  const float* q  = (const float*)d_in[0];
  const float* k  = (const float*)d_in[1];
  const float* v  = (const float*)d_in[2];
  const float* Wq = (const float*)d_in[3];
  const float* bq = (const float*)d_in[4];
  const float* Wk = (const float*)d_in[5];
  const float* bk = (const float*)d_in[6];
  const float* Wv = (const float*)d_in[7];
  const float* bv = (const float*)d_in[8];
  const float* Wo = (const float*)d_in[9];
  const float* bo = (const float*)d_in[10];

  __bf16* ws = (__bf16*)d_ws;
  __bf16 *Wq_b = ws + WS_WQ, *Wk_b = ws + WS_WK, *Wv_b = ws + WS_WV, *Wo_b = ws + WS_WO;
  __bf16 *Qh = ws + WS_QH, *Kh = ws + WS_KH, *Vt = ws + WS_VT;
  __bf16 *AO = ws + WS_AO;

  convert_w<<<2048, 256, 0, stream>>>(Wq, Wk, Wv, Wo, ws);

  qkv_gemm<<<dim3(GN / 128, GM / 128, 3), 256, 0, stream>>>(
      q, k, v, Wq_b, Wk_b, Wv_b, bq, bk, bv, Qh, Kh, Vt);

  attn<<<dim3(CB * CH, CS / 128), 256, 0, stream>>>(Qh, Kh, Vt, AO);

  gemm_wo<<<dim3(GN / 128, GM / 64), 256, 0, stream>>>(AO, Wo_b, bo, (float*)d_out);
}